// Round 9
// baseline (351.676 us; speedup 1.0000x reference)
//
#include <hip/hip_runtime.h>
#include <math.h>

// ---------------- workspace layout (bytes) ----------------
#define X_B      0         // 512*1024 f32   = 2,097,152
#define BBOX_B   2097152   // 36*1024 f32    = 147,456
#define PROPS_B  2244608   // 9216 float4    = 147,456
#define KEYS_B   2392064   // 9216 u64       = 73,728   (reused as intra)
#define RANK_B   2465792   // 9216 u32       = 36,864
#define SKEYS_B  2502656   // 9216 u64       = 73,728
#define SBOX_B   2576384   // 9216 float4    = 147,456
#define MASK_B   2725888   // 9216*144 u64   = 10,616,832 (end 13,342,720)
#define INTRA_B  KEYS_B    // 144*64 u64     = 73,728 (keys dead after scatter_k)
#define WS_NEED  13400000

typedef unsigned long long u64;

// ---- DPP lane exchange (within 16-lane DPP rows; OOB lanes -> 0) ----
__device__ __forceinline__ float dpp_shr1(float x) {
  return __int_as_float(__builtin_amdgcn_update_dpp(
      0, __float_as_int(x), 0x111, 0xF, 0xF, true));
}
__device__ __forceinline__ float dpp_shl1(float x) {
  return __int_as_float(__builtin_amdgcn_update_dpp(
      0, __float_as_int(x), 0x101, 0xF, 0xF, true));
}

// ================= conv 3x3 (256->512, 32x32, pad 1) + ReLU =================
// v4: 1024 blocks = (channel-pair cp, image QUARTER qi) -> 4 blocks/CU,
// 32 waves/CU (fp64-FMA issue-bound; more waves cover s_load/ds latency).
// 512 threads = 4 K-groups (64ch) x 128 px-threads (2px x 2ch, 4 fp64 accs).
// LDS tile: 2ch x 10 rows x pitch36, no halo, double-buffered; +-1 columns
// via DPP; weights pipelined fp32 scalar loads (SGPR), cvt at use.
#define TP    36
#define TROWS 10
#define TCH2  (TROWS * TP)     // 360 floats per channel slice

__global__ __launch_bounds__(512, 4) void conv3x3_relu_k(
    const float* __restrict__ feat, const float* __restrict__ w,
    const float* __restrict__ bias, float* __restrict__ xout)
{
  __shared__ __align__(16) float smf[4][2][2 * TCH2];   // 23,040 B
  const int cp = blockIdx.x >> 2, qi = blockIdx.x & 3;
  const int tid = threadIdx.x;
  const int kg = __builtin_amdgcn_readfirstlane(tid >> 7);  // 0..3
  const int t = tid & 127;
  const int r8 = qi << 3;              // first output row of quarter
  const int co0 = cp << 1;
  const int kbase = kg << 6;

  for (int i = tid; i < 4 * 2 * 2 * TCH2; i += 512) ((float*)smf)[i] = 0.0f;

  const int yl = t >> 4;               // 0..7 local row
  const int x0 = (t & 15) << 1;        // 0,2,...,30
  double aA0 = 0.0, aA1 = 0.0, aB0 = 0.0, aB1 = 0.0;

  const float4* feat4 = (const float4*)feat;
  // staging: 2ch x 10 rows x 8 float4 = 160 float4 over 128 thr -> 2 slots
  float4 pf[2]; int pch[2], prow[2], pc4[2]; bool pok[2];
  #pragma unroll
  for (int k = 0; k < 2; ++k) {
    const int i = t + (k << 7);
    const int ch = i / 80, rem = i - ch * 80;
    const int row = rem >> 3, c4 = rem & 7;
    const int g = r8 - 1 + row;
    pch[k] = ch; prow[k] = row; pc4[k] = c4;
    pok[k] = (i < 160) && ((unsigned)g < 32u);
    pf[k] = pok[k] ? feat4[((kbase + ch) << 8) + (g << 3) + c4]
                   : float4{0.f, 0.f, 0.f, 0.f};
  }

  float fa0[9], fb0[9], fa1[9], fb1[9];
  {
    const float* p = w + co0 * 2304 + kbase * 9;
    #pragma unroll
    for (int q = 0; q < 9; ++q) { fa0[q] = p[q]; fb0[q] = p[q + 2304]; }
  }
  __syncthreads();                     // zero-init visible

  #define CONV_CL2(IR, FA, FB)                                                \
    {                                                                         \
      const float* ir = (IR);                                                 \
      _Pragma("unroll")                                                       \
      for (int ky = 0; ky < 3; ++ky) {                                        \
        const float2 q = *(const float2*)(ir + ky * TP);                      \
        float vl = dpp_shr1(q.y); if (x0 == 0)  vl = 0.f;                     \
        float vr = dpp_shl1(q.x); if (x0 == 30) vr = 0.f;                     \
        const double d0 = (double)vl, d1 = (double)q.x;                       \
        const double d2 = (double)q.y, d3 = (double)vr;                       \
        const double w0 = (double)FA[3*ky],   w1 = (double)FA[3*ky+1];        \
        const double w2 = (double)FA[3*ky+2];                                 \
        const double u0 = (double)FB[3*ky],   u1 = (double)FB[3*ky+1];        \
        const double u2 = (double)FB[3*ky+2];                                 \
        aA0 += d0*w0 + d1*w1 + d2*w2;  aA1 += d1*w0 + d2*w1 + d3*w2;          \
        aB0 += d0*u0 + d1*u1 + d2*u2;  aB1 += d1*u0 + d2*u1 + d3*u2;          \
      }                                                                       \
    }

  for (int tt = 0; tt < 32; ++tt) {
    const int buf = tt & 1;
    #pragma unroll
    for (int k = 0; k < 2; ++k)
      if (pok[k])
        *(float4*)&smf[kg][buf][pch[k] * TCH2 + prow[k] * TP + (pc4[k] << 2)] = pf[k];
    if (tt < 31) {
      #pragma unroll
      for (int k = 0; k < 2; ++k) {
        const int g = r8 - 1 + prow[k];
        if (pok[k])
          pf[k] = feat4[((kbase + 2 * (tt + 1) + pch[k]) << 8) + (g << 3) + pc4[k]];
      }
    }
    __syncthreads();                   // tile ready (single barrier per tile)
    {
      const float* p = w + co0 * 2304 + (kbase + 2 * tt + 1) * 9;
      #pragma unroll
      for (int q = 0; q < 9; ++q) { fa1[q] = p[q]; fb1[q] = p[q + 2304]; }
    }
    CONV_CL2(&smf[kg][buf][yl * TP + x0], fa0, fb0);          // cl = 0
    {
      int ci = kbase + 2 * tt + 2; if (ci > 255) ci = 255;    // dummy at end
      const float* p = w + co0 * 2304 + ci * 9;
      #pragma unroll
      for (int q = 0; q < 9; ++q) { fa0[q] = p[q]; fb0[q] = p[q + 2304]; }
    }
    CONV_CL2(&smf[kg][buf][TCH2 + yl * TP + x0], fa1, fb1);   // cl = 1
  }

  // cross-K-group reduce (red overlays smf; all compute reads are done)
  __syncthreads();
  double (*red)[4] = (double(*)[4]) & smf[0][0][0];           // 3*128*4 doubles
  if (kg < 3) {
    double* rp = red[(kg << 7) + t];
    rp[0] = aA0; rp[1] = aA1; rp[2] = aB0; rp[3] = aB1;
  }
  __syncthreads();
  if (kg == 3) {
    const double bA = (double)bias[co0], bB = (double)bias[co0 + 1];
    const double* r0 = red[t];
    const double* r1 = red[128 + t];
    const double* r2 = red[256 + t];
    const int y = r8 + yl;
    float2 RA, RB;
    RA.x = (float)fmax(r0[0] + r1[0] + r2[0] + aA0 + bA, 0.0);
    RA.y = (float)fmax(r0[1] + r1[1] + r2[1] + aA1 + bA, 0.0);
    RB.x = (float)fmax(r0[2] + r1[2] + r2[2] + aB0 + bB, 0.0);
    RB.y = (float)fmax(r0[3] + r1[3] + r2[3] + aB1 + bB, 0.0);
    *(float2*)&xout[(co0 << 10) + (y << 5) + x0] = RA;
    *(float2*)&xout[((co0 + 1) << 10) + (y << 5) + x0] = RB;
  }
}

// ========== fallback conv (small ws) ========================================
#define CPITCH 38
#define CCHS   (18 * CPITCH)
__global__ __launch_bounds__(256) void conv3x3_relu_fb_k(
    const float* __restrict__ feat, const float* __restrict__ w,
    const float* __restrict__ bias, float* __restrict__ xout)
{
  __shared__ float il[2][8 * CCHS];
  const int cp = blockIdx.x >> 1, h = blockIdx.x & 1;
  const int tid = threadIdx.x;
  const int h16 = h << 4;
  const int co0 = cp << 1;
  for (int i = tid; i < 8 * CCHS; i += 256) { il[0][i] = 0.0f; il[1][i] = 0.0f; }
  const int yl = tid >> 4;
  const int x0 = (tid & 15) << 1;
  double aA0 = 0.0, aA1 = 0.0, aB0 = 0.0, aB1 = 0.0;
  const float4* feat4 = (const float4*)feat;
  float4 pf[5]; int pch[5], pt[5], pc4[5], pok[5];
  #pragma unroll
  for (int k = 0; k < 5; ++k) {
    const int i = tid + (k << 8);
    const int ch = i / 144, rem = i - ch * 144;
    const int t = rem >> 3, c4 = rem & 7;
    const int g = h16 - 1 + t;
    pch[k] = ch; pt[k] = t; pc4[k] = c4;
    pok[k] = (i < 1152) && ((unsigned)g < 32u);
    pf[k] = pok[k] ? feat4[(ch << 8) + (g << 3) + c4] : float4{0.f,0.f,0.f,0.f};
  }
  __syncthreads();
  for (int cc = 0; cc < 256; cc += 8) {
    const int buf = (cc >> 3) & 1;
    #pragma unroll
    for (int k = 0; k < 5; ++k)
      if (pok[k]) {
        float* p = &il[buf][pch[k] * CCHS + pt[k] * CPITCH + (pc4[k] << 2) + 1];
        p[0] = pf[k].x; p[1] = pf[k].y; p[2] = pf[k].z; p[3] = pf[k].w;
      }
    if (cc + 8 < 256) {
      #pragma unroll
      for (int k = 0; k < 5; ++k) {
        const int g = h16 - 1 + pt[k];
        if (pok[k]) pf[k] = feat4[((cc + 8 + pch[k]) << 8) + (g << 3) + pc4[k]];
      }
    }
    __syncthreads();
    #pragma unroll
    for (int cl = 0; cl < 8; ++cl) {
      const float* wAp = w + co0 * 2304 + (cc + cl) * 9;
      const float* wBp = wAp + 2304;
      double wa[9], wb[9];
      #pragma unroll
      for (int q = 0; q < 9; ++q) { wa[q] = (double)wAp[q]; wb[q] = (double)wBp[q]; }
      const float* ir = &il[buf][cl * CCHS + yl * CPITCH + x0];
      #pragma unroll
      for (int ky = 0; ky < 3; ++ky) {
        const float2 q0 = *(const float2*)(ir + ky * CPITCH);
        const float2 q1 = *(const float2*)(ir + ky * CPITCH + 2);
        const double v0 = (double)q0.x, v1 = (double)q0.y;
        const double v2 = (double)q1.x, v3 = (double)q1.y;
        aA0 += v0 * wa[3*ky+0] + v1 * wa[3*ky+1] + v2 * wa[3*ky+2];
        aA1 += v1 * wa[3*ky+0] + v2 * wa[3*ky+1] + v3 * wa[3*ky+2];
        aB0 += v0 * wb[3*ky+0] + v1 * wb[3*ky+1] + v2 * wb[3*ky+2];
        aB1 += v1 * wb[3*ky+0] + v2 * wb[3*ky+1] + v3 * wb[3*ky+2];
      }
    }
  }
  const double bA = (double)bias[co0], bB = (double)bias[co0 + 1];
  const int y = h16 + yl;
  float2 rA, rB;
  rA.x = (float)fmax(aA0 + bA, 0.0); rA.y = (float)fmax(aA1 + bA, 0.0);
  rB.x = (float)fmax(aB0 + bB, 0.0); rB.y = (float)fmax(aB1 + bB, 0.0);
  *(float2*)&xout[(co0 << 10) + (y << 5) + x0] = rA;
  *(float2*)&xout[((co0 + 1) << 10) + (y << 5) + x0] = rB;
}

// ================= 1x1 heads ================================================
__global__ __launch_bounds__(256) void head1x1_k(
    const float* __restrict__ x,
    const float* __restrict__ cls_w, const float* __restrict__ cls_b,
    const float* __restrict__ bbox_w, const float* __restrict__ bbox_b,
    float* __restrict__ out, float* __restrict__ bbox_out)
{
  __shared__ float wl[512];
  const int bid = blockIdx.x;
  const int co = bid >> 2;
  const int px = ((bid & 3) << 8) | threadIdx.x;
  const bool is_cls = co < 18;
  const float* wsrc = is_cls ? (cls_w + co * 512) : (bbox_w + (co - 18) * 512);
  for (int i = threadIdx.x; i < 512; i += 256) wl[i] = wsrc[i];
  __syncthreads();
  double acc0 = 0.0, acc1 = 0.0, acc2 = 0.0, acc3 = 0.0;
  #pragma unroll 4
  for (int c = 0; c < 512; c += 4) {
    acc0 += (double)x[((c + 0) << 10) | px] * (double)wl[c + 0];
    acc1 += (double)x[((c + 1) << 10) | px] * (double)wl[c + 1];
    acc2 += (double)x[((c + 2) << 10) | px] * (double)wl[c + 2];
    acc3 += (double)x[((c + 3) << 10) | px] * (double)wl[c + 3];
  }
  double acc = ((acc0 + acc1) + (acc2 + acc3)) +
               (double)(is_cls ? cls_b[co] : bbox_b[co - 18]);
  if (is_cls)
    out[36864 + (co << 10) + px] = (float)(1.0 / (1.0 + exp(-acc)));
  else
    bbox_out[((co - 18) << 10) + px] = (float)acc;
}

// ============ anchors + box decode + clip + key build =======================
__global__ __launch_bounds__(256) void proposals_k(
    const float* __restrict__ bbox, const int* __restrict__ imgsz,
    const float* __restrict__ out, float* __restrict__ props,
    u64* __restrict__ keys, unsigned* __restrict__ rank)
{
  const int r = blockIdx.x * 256 + threadIdx.x;
  if (r >= 9216) return;
  const float4 d = ((const float4*)bbox)[r];
  const int cell = r / 9, a = r - cell * 9;
  const int ix = cell & 31, iy = cell >> 5;
  const int ri = a / 3, si = a - ri * 3;
  const double ratio = (ri == 0) ? 0.5 : (ri == 1 ? 1.0 : 2.0);
  const double scale = (si == 0) ? 128.0 : (si == 1 ? 256.0 : 512.0);
  const double hr = sqrt(ratio), wr = 1.0 / hr;
  const double bx = nearbyint(wr * scale * 0.5);
  const double by = nearbyint(hr * scale * 0.5);
  const double cx = ix * 16.0, cy = iy * 16.0;
  const double w = 2.0 * bx, hh = 2.0 * by;
  const double pcx = (double)d.x * w + cx;
  const double pcy = (double)d.y * hh + cy;
  const double pw = exp((double)d.z) * w;
  const double ph = exp((double)d.w) * hh;
  const double im = (double)imgsz[0];
  float4 o;
  o.x = (float)fmin(fmax(pcx - 0.5 * pw, 0.0), im);
  o.y = (float)fmin(fmax(pcy - 0.5 * ph, 0.0), im);
  o.z = (float)fmin(fmax(pcx + 0.5 * pw, 0.0), im);
  o.w = (float)fmin(fmax(pcy + 0.5 * ph, 0.0), im);
  ((float4*)props)[r] = o;
  const float s = out[36864 + ((2 * (r >> 10) + 1) << 10) + (r & 1023)];
  keys[r] = ((u64)__float_as_uint(s) << 32) | (unsigned)(0x7FFFFFFF - r);
  rank[r] = 0u;
}

// ================= rank sort ================================================
__global__ __launch_bounds__(256) void rank_k(
    const u64* __restrict__ keys, unsigned* __restrict__ rank)
{
  const int jt = blockIdx.x % 36, ic = blockIdx.x / 36;
  const int j = jt * 256 + threadIdx.x;
  const u64 kj = keys[j];
  const int lane = threadIdx.x & 63;
  const int base = ic * 576;
  unsigned lo[9], hi[9];
  #pragma unroll
  for (int rr = 0; rr < 9; ++rr) {
    const u64 k = keys[base + rr * 64 + lane];
    lo[rr] = (unsigned)k; hi[rr] = (unsigned)(k >> 32);
  }
  unsigned cnt = 0;
  #pragma unroll
  for (int rr = 0; rr < 9; ++rr) {
    #pragma unroll
    for (int l = 0; l < 64; ++l) {
      const unsigned llo = (unsigned)__builtin_amdgcn_readlane((int)lo[rr], l);
      const unsigned lhi = (unsigned)__builtin_amdgcn_readlane((int)hi[rr], l);
      const u64 ki = ((u64)lhi << 32) | llo;
      cnt += (ki > kj) ? 1u : 0u;
    }
  }
  atomicAdd(&rank[j], cnt);
}

// ================= scatter into sorted order ================================
__global__ __launch_bounds__(256) void scatter_k(
    const u64* __restrict__ keys, const unsigned* __restrict__ rank,
    const float* __restrict__ props, u64* __restrict__ skeys,
    float4* __restrict__ sboxes)
{
  const int r = blockIdx.x * 256 + threadIdx.x;
  if (r >= 9216) return;
  const unsigned rk = rank[r];
  skeys[rk] = keys[r];
  sboxes[rk] = ((const float4*)props)[r];
}

// ====== suppression bitmask + intra-word columns (LDS-staged i-boxes) =======
__global__ __launch_bounds__(256) void mask_k(
    const float4* __restrict__ sb4, u64* __restrict__ mask,
    u64* __restrict__ intra)
{
  __shared__ __align__(16) float4 ib[128];
  const int ci = blockIdx.x;                  // 0..71
  const int Wb = blockIdx.y << 2;             // first word of quad
  const int i_lo = ci << 7;
  const int i_hi_blk = min(i_lo + 128, (Wb + 4) << 6);
  if (i_lo >= i_hi_blk) return;               // uniform across block
  const int wv = threadIdx.x >> 6, lane = threadIdx.x & 63;
  const int W = Wb + wv;
  const int cnt = i_hi_blk - i_lo;
  for (int k = threadIdx.x; k < cnt; k += 256) ib[k] = sb4[i_lo + k];
  __syncthreads();
  const float4 bj = sb4[(W << 6) + lane];
  const float areaJ = (bj.z - bj.x) * (bj.w - bj.y);
  const int wbase = W << 6;
  const int n = min(i_hi_blk, wbase + 64) - i_lo;   // may be <=0
  u64 intr = 0ULL;
  #pragma unroll 4
  for (int k = 0; k < n; ++k) {
    const float4 bi = ib[k];
    const float areaI = (bi.z - bi.x) * (bi.w - bi.y);
    const float ix1 = fmaxf(bj.x, bi.x), iy1 = fmaxf(bj.y, bi.y);
    const float ix2 = fminf(bj.z, bi.z), iy2 = fminf(bj.w, bi.w);
    const float iw = fmaxf(ix2 - ix1, 0.0f), ih = fmaxf(iy2 - iy1, 0.0f);
    const double inter = (double)iw * (double)ih;
    const double uni = (double)areaJ + (double)areaI - inter + 1e-9;
    const bool pred = inter > 0.3 * uni;
    const u64 bal = __ballot(pred);
    const int i = i_lo + k;
    if (lane == 0) mask[(size_t)i * 144 + W] = bal;
    if (i >= wbase) intr |= pred ? (1ULL << (i - wbase)) : 0ULL;
  }
  if ((wbase >> 7) == ci) intra[wbase + lane] = intr;   // diagonal chunk
}

// ====== sweep v3.1: supergroup-LDS exact sequential NMS + output ============
// Same as R8 but the pull phase is unrolled x8 (8 independent HBM loads in
// flight instead of 1 -> latency/8; this was the hidden serial cost).
__global__ __launch_bounds__(1024) void sweep_out_k(
    const u64* __restrict__ mask, const u64* __restrict__ intra,
    const u64* __restrict__ skeys, const float4* __restrict__ sboxes,
    float* __restrict__ out)
{
  extern __shared__ __align__(16) char sm[];
  u64* subm   = (u64*)sm;                       // 16384 u64 = 131072 B
  u64* intraS = subm + 16384;                   // 1024 u64  = 8192 B
  u64* supS   = intraS + 1024;                  // 16 u64    = 128 B
  u64* keptS  = supS + 16;                      // 144 u64   = 1152 B
  unsigned short* kpl = (unsigned short*)(keptS + 144);  // 9216 u16 = 18432 B
  int* kcnt = (int*)(kpl + 9216);               // 4 B   (total 158,980)

  const int tid = threadIdx.x;
  const int lane = tid & 63, wv = tid >> 6;
  if (tid == 0) *kcnt = 0;
  if (tid < 144) keptS[tid] = 0ULL;

  for (int sg = 0; sg < 9; ++sg) {
    const int wbase = sg << 4;
    const int ibase = wbase << 6;
    __syncthreads();                       // prev sg resolved; buffers free
    if (tid < 16) supS[tid] = 0ULL;
    {                                      // stage sub-mask, coalesced by word
      const int wq = tid & 15, r0 = tid >> 4;        // r0: 0..63
      #pragma unroll
      for (int k = 0; k < 16; ++k) {
        const int i = r0 + (k << 6);
        subm[i * 16 + wq] = mask[(size_t)(ibase + i) * 144 + wbase + wq];
      }
    }
    intraS[tid] = intra[ibase + tid];
    __syncthreads();                       // supS zeroed, staging visible
    {                                      // pull prior-kept suppression (x8)
      const int K = *kcnt;
      const int wq = tid & 15;
      u64 acc = 0ULL;
      int jj = tid >> 4;
      for (; jj + 7 * 64 < K; jj += 8 * 64) {
        const u64 v0 = mask[(size_t)kpl[jj + 0 * 64] * 144 + wbase + wq];
        const u64 v1 = mask[(size_t)kpl[jj + 1 * 64] * 144 + wbase + wq];
        const u64 v2 = mask[(size_t)kpl[jj + 2 * 64] * 144 + wbase + wq];
        const u64 v3 = mask[(size_t)kpl[jj + 3 * 64] * 144 + wbase + wq];
        const u64 v4 = mask[(size_t)kpl[jj + 4 * 64] * 144 + wbase + wq];
        const u64 v5 = mask[(size_t)kpl[jj + 5 * 64] * 144 + wbase + wq];
        const u64 v6 = mask[(size_t)kpl[jj + 6 * 64] * 144 + wbase + wq];
        const u64 v7 = mask[(size_t)kpl[jj + 7 * 64] * 144 + wbase + wq];
        acc |= ((v0 | v1) | (v2 | v3)) | ((v4 | v5) | (v6 | v7));
      }
      for (; jj < K; jj += 64)
        acc |= mask[(size_t)kpl[jj] * 144 + wbase + wq];
      if (acc) {
        atomicOr((unsigned*)&supS[wq], (unsigned)acc);
        atomicOr(((unsigned*)&supS[wq]) + 1, (unsigned)(acc >> 32));
      }
    }
    __syncthreads();
    if (wv == 0) {
      u64 myAlive = (lane < 16) ? ~supS[lane] : 0ULL;   // lane l: word wbase+l
      for (int w = 0; w < 16; ++w) {
        const u64 av = __shfl(myAlive, w, 64);
        if (av == 0ULL) continue;
        const u64 il_ = intraS[(w << 6) + lane];
        u64 cand = av, keptw = 0ULL;
        while (cand) {
          const int b = (int)__builtin_ctzll(cand);   // uniform
          keptw |= 1ULL << b;
          cand &= ~(1ULL << b);
          const u64 sup = __ballot((il_ >> b) & 1ULL);
          cand &= ~sup;
        }
        if (lane == 0) {
          keptS[wbase + w] = keptw;
          int K = *kcnt;
          u64 t = keptw;
          while (t) {
            const int b = (int)__builtin_ctzll(t); t &= t - 1ULL;
            kpl[K++] = (unsigned short)(ibase + (w << 6) + b);
          }
          *kcnt = K;
        }
        // apply kept rows (batch 4 per ds_read round)
        u64 t = keptw;
        while (t) {
          int bs[4]; int n = 0;
          #pragma unroll
          for (int s = 0; s < 4; ++s) {
            if (t) { bs[s] = (int)__builtin_ctzll(t); t &= t - 1ULL; n = s + 1; }
            else bs[s] = 0;
          }
          const int kk = lane >> 4, wq = lane & 15;
          u64 r = (kk < n) ? subm[((w << 6) + bs[kk]) * 16 + wq] : 0ULL;
          r |= __shfl_down(r, 16, 64);
          r |= __shfl_down(r, 32, 64);
          // lane l<16 now holds OR of all <=4 kept rows for word wbase+l
          myAlive &= ~r;
        }
      }
    }
  }
  __syncthreads();
  for (int i = tid; i < 9216; i += 1024) {
    const u64 key = skeys[i];
    const int orig = 0x7FFFFFFF - (int)(unsigned)(key & 0xFFFFFFFFULL);
    const bool kp = (keptS[i >> 6] >> (i & 63)) & 1ULL;
    float4 ob = sboxes[i];
    if (!kp) { ob.x = 0.f; ob.y = 0.f; ob.z = 0.f; ob.w = 0.f; }
    ((float4*)out)[orig] = ob;
    out[55296 + orig] = kp ? 1.0f : 0.0f;
  }
}

// ================= fallback NMS (small ws) ==================================
__global__ __launch_bounds__(1024) void nms_fallback_k(
    const float* __restrict__ props, float* __restrict__ out)
{
  __shared__ u64 wmax[16];
  __shared__ float4 curBoxS;
  const int tid = threadIdx.x, wid = tid >> 6, lane = tid & 63;
  u64 key[9];
  float4 box[9];
  #pragma unroll
  for (int j = 0; j < 9; ++j) {
    const int r = tid + (j << 10);
    box[j] = ((const float4*)props)[r];
    const float s = out[36864 + ((2 * (r >> 10) + 1) << 10) + (r & 1023)];
    key[j] = ((u64)__float_as_uint(s) << 32) | (unsigned)(0x7FFFFFFF - r);
  }
  unsigned kept = 0;
  for (;;) {
    u64 m = key[0];
    #pragma unroll
    for (int j = 1; j < 9; ++j) m = key[j] > m ? key[j] : m;
    #pragma unroll
    for (int off = 32; off; off >>= 1) {
      const u64 o = __shfl_down(m, off, 64);
      if (o > m) m = o;
    }
    if (lane == 0) wmax[wid] = m;
    __syncthreads();
    u64 K = wmax[0];
    #pragma unroll
    for (int wv2 = 1; wv2 < 16; ++wv2) { const u64 t = wmax[wv2]; if (t > K) K = t; }
    if (K == 0) break;
    #pragma unroll
    for (int j = 0; j < 9; ++j)
      if (key[j] == K) { curBoxS = box[j]; key[j] = 0; kept |= 1u << j; }
    __syncthreads();
    const float4 cb = curBoxS;
    const float areaC = (cb.z - cb.x) * (cb.w - cb.y);
    #pragma unroll
    for (int j = 0; j < 9; ++j) {
      if (key[j]) {
        const float4 b = box[j];
        const float ix1 = fmaxf(b.x, cb.x), iy1 = fmaxf(b.y, cb.y);
        const float ix2 = fminf(b.z, cb.z), iy2 = fminf(b.w, cb.w);
        const float iw = fmaxf(ix2 - ix1, 0.0f), ih = fmaxf(iy2 - iy1, 0.0f);
        const float areaB = (b.z - b.x) * (b.w - b.y);
        const double inter = (double)iw * (double)ih;
        const double uni = (double)areaB + (double)areaC - inter + 1e-9;
        if (inter > 0.3 * uni) key[j] = 0;
      }
    }
    __syncthreads();
  }
  #pragma unroll
  for (int j = 0; j < 9; ++j) {
    const int r = tid + (j << 10);
    const bool kp = (kept >> j) & 1u;
    float4 ob = box[j];
    if (!kp) { ob.x = 0.f; ob.y = 0.f; ob.z = 0.f; ob.w = 0.f; }
    ((float4*)out)[r] = ob;
    out[55296 + r] = kp ? 1.0f : 0.0f;
  }
}

// ============================================================================
extern "C" void kernel_launch(void* const* d_in, const int* in_sizes, int n_in,
                              void* d_out, int out_size, void* d_ws, size_t ws_size,
                              hipStream_t stream)
{
  const float* feat   = (const float*)d_in[0];
  const int*   imgsz  = (const int*)d_in[1];
  const float* conv_w = (const float*)d_in[2];
  const float* conv_b = (const float*)d_in[3];
  const float* cls_w  = (const float*)d_in[4];
  const float* cls_b  = (const float*)d_in[5];
  const float* bbox_w = (const float*)d_in[6];
  const float* bbox_b = (const float*)d_in[7];
  float* out = (float*)d_out;
  char*  ws  = (char*)d_ws;
  float* x      = (float*)(ws + X_B);
  float* bbox   = (float*)(ws + BBOX_B);
  float* props  = (float*)(ws + PROPS_B);
  u64*      keys  = (u64*)(ws + KEYS_B);
  unsigned* rankp = (unsigned*)(ws + RANK_B);
  u64*      skeys = (u64*)(ws + SKEYS_B);
  float4*   sboxs = (float4*)(ws + SBOX_B);
  u64*      maskp = (u64*)(ws + MASK_B);
  u64*      intrp = (u64*)(ws + INTRA_B);

  if (ws_size >= (size_t)WS_NEED) {
    hipLaunchKernelGGL(conv3x3_relu_k, dim3(1024), dim3(512), 0, stream,
                       feat, conv_w, conv_b, x);
    hipLaunchKernelGGL(head1x1_k, dim3(216), dim3(256), 0, stream,
                       x, cls_w, cls_b, bbox_w, bbox_b, out, bbox);
    hipLaunchKernelGGL(proposals_k, dim3(36), dim3(256), 0, stream,
                       bbox, imgsz, out, props, keys, rankp);
    hipLaunchKernelGGL(rank_k, dim3(576), dim3(256), 0, stream, keys, rankp);
    hipLaunchKernelGGL(scatter_k, dim3(36), dim3(256), 0, stream,
                       keys, rankp, props, skeys, sboxs);
    hipLaunchKernelGGL(mask_k, dim3(72, 36), dim3(256), 0, stream,
                       sboxs, maskp, intrp);
    hipLaunchKernelGGL(sweep_out_k, dim3(1), dim3(1024), 158984, stream,
                       maskp, intrp, skeys, sboxs, out);
  } else {
    hipLaunchKernelGGL(conv3x3_relu_fb_k, dim3(512), dim3(256), 0, stream,
                       feat, conv_w, conv_b, x);
    hipLaunchKernelGGL(head1x1_k, dim3(216), dim3(256), 0, stream,
                       x, cls_w, cls_b, bbox_w, bbox_b, out, bbox);
    hipLaunchKernelGGL(proposals_k, dim3(36), dim3(256), 0, stream,
                       bbox, imgsz, out, props, keys, rankp);
    hipLaunchKernelGGL(nms_fallback_k, dim3(1), dim3(1024), 0, stream,
                       props, out);
  }
}

// Round 10
// 318.920 us; speedup vs baseline: 1.1027x; 1.1027x over previous
//
#include <hip/hip_runtime.h>
#include <math.h>

// ---------------- workspace layout (bytes) ----------------
#define X_B      0         // 512*1024 f32   = 2,097,152
#define BBOX_B   2097152   // 36*1024 f32    = 147,456
#define PROPS_B  2244608   // 9216 float4    = 147,456
#define KEYS_B   2392064   // 9216 u64       = 73,728   (reused as intra)
#define RANK_B   2465792   // 9216 u32       = 36,864
#define SKEYS_B  2502656   // 9216 u64       = 73,728
#define SBOX_B   2576384   // 9216 float4    = 147,456
#define MASK_B   2725888   // 9216*144 u64   = 10,616,832 (end 13,342,720)
#define INTRA_B  KEYS_B    // 144*64 u64     = 73,728 (keys dead after scatter_k)
#define WS_NEED  13400000

typedef unsigned long long u64;

// ---- DPP lane exchange (within 16-lane DPP rows; OOB lanes -> 0) ----
__device__ __forceinline__ float dpp_shr1(float x) {
  return __int_as_float(__builtin_amdgcn_update_dpp(
      0, __float_as_int(x), 0x111, 0xF, 0xF, true));
}
__device__ __forceinline__ float dpp_shl1(float x) {
  return __int_as_float(__builtin_amdgcn_update_dpp(
      0, __float_as_int(x), 0x101, 0xF, 0xF, true));
}

// ================= conv 3x3 (256->512, 32x32, pad 1) + ReLU =================
// REVERTED to R8 (measured 102.5-103 us, VALUBusy ~67%): 512 blocks =
// (channel-pair, image-half), 512 thr = 4 K-groups x 128 px-threads
// (4px x 2ch). R9's 2px variant regressed (cvt overhead per FMA doubled).
#define TP  36
#define TCH 648

__global__ __launch_bounds__(512, 4) void conv3x3_relu_k(
    const float* __restrict__ feat, const float* __restrict__ w,
    const float* __restrict__ bias, float* __restrict__ xout)
{
  __shared__ __align__(16) float smf[4][2][2 * TCH];   // 41,472 B
  const int cp = blockIdx.x >> 1, himg = blockIdx.x & 1;
  const int tid = threadIdx.x;
  const int kg = __builtin_amdgcn_readfirstlane(tid >> 7);
  const int t = tid & 127;
  const int h16 = himg << 4;
  const int co0 = cp << 1;
  const int kbase = kg << 6;

  for (int i = tid; i < 4 * 2 * 2 * TCH; i += 512) ((float*)smf)[i] = 0.0f;

  const int yl = t >> 3;            // 0..15
  const int x0 = (t & 7) << 2;      // 0,4,...,28
  double aA[4] = {0,0,0,0}, aB[4] = {0,0,0,0};

  const float4* feat4 = (const float4*)feat;
  float4 pf[3]; int pch[3], prow[3], pc4[3]; bool pok[3];
  #pragma unroll
  for (int k = 0; k < 3; ++k) {
    const int i = t + (k << 7);
    const int ch = i / 144, rem = i - ch * 144;
    const int row = rem >> 3, c4 = rem & 7;
    const int g = h16 - 1 + row;
    pch[k] = ch; prow[k] = row; pc4[k] = c4;
    pok[k] = (i < 288) && ((unsigned)g < 32u);
    pf[k] = pok[k] ? feat4[((kbase + ch) << 8) + (g << 3) + c4]
                   : float4{0.f, 0.f, 0.f, 0.f};
  }

  float fa0[9], fb0[9], fa1[9], fb1[9];
  {
    const float* p = w + co0 * 2304 + kbase * 9;
    #pragma unroll
    for (int q = 0; q < 9; ++q) { fa0[q] = p[q]; fb0[q] = p[q + 2304]; }
  }
  __syncthreads();

  #define CONV_CL(IR, FA, FB)                                                 \
    {                                                                         \
      const float* ir = (IR);                                                 \
      _Pragma("unroll")                                                       \
      for (int ky = 0; ky < 3; ++ky) {                                        \
        const float4 q = *(const float4*)(ir + ky * TP);                      \
        float vl = dpp_shr1(q.w); if (x0 == 0)  vl = 0.f;                     \
        float vr = dpp_shl1(q.x); if (x0 == 28) vr = 0.f;                     \
        const double d0 = (double)vl,  d1 = (double)q.x, d2 = (double)q.y;    \
        const double d3 = (double)q.z, d4 = (double)q.w, d5 = (double)vr;     \
        const double w0 = (double)FA[3*ky],   w1 = (double)FA[3*ky+1];        \
        const double w2 = (double)FA[3*ky+2];                                 \
        const double u0 = (double)FB[3*ky],   u1 = (double)FB[3*ky+1];        \
        const double u2 = (double)FB[3*ky+2];                                 \
        aA[0] += d0*w0 + d1*w1 + d2*w2;  aA[1] += d1*w0 + d2*w1 + d3*w2;      \
        aA[2] += d2*w0 + d3*w1 + d4*w2;  aA[3] += d3*w0 + d4*w1 + d5*w2;      \
        aB[0] += d0*u0 + d1*u1 + d2*u2;  aB[1] += d1*u0 + d2*u1 + d3*u2;      \
        aB[2] += d2*u0 + d3*u1 + d4*u2;  aB[3] += d3*u0 + d4*u1 + d5*u2;      \
      }                                                                       \
    }

  for (int tt = 0; tt < 32; ++tt) {
    const int buf = tt & 1;
    #pragma unroll
    for (int k = 0; k < 3; ++k)
      if (pok[k])
        *(float4*)&smf[kg][buf][pch[k] * TCH + prow[k] * TP + (pc4[k] << 2)] = pf[k];
    if (tt < 31) {
      #pragma unroll
      for (int k = 0; k < 3; ++k) {
        const int g = h16 - 1 + prow[k];
        if (pok[k])
          pf[k] = feat4[((kbase + 2 * (tt + 1) + pch[k]) << 8) + (g << 3) + pc4[k]];
      }
    }
    __syncthreads();
    {
      const float* p = w + co0 * 2304 + (kbase + 2 * tt + 1) * 9;
      #pragma unroll
      for (int q = 0; q < 9; ++q) { fa1[q] = p[q]; fb1[q] = p[q + 2304]; }
    }
    CONV_CL(&smf[kg][buf][yl * TP + x0], fa0, fb0);
    {
      int ci = kbase + 2 * tt + 2; if (ci > 255) ci = 255;
      const float* p = w + co0 * 2304 + ci * 9;
      #pragma unroll
      for (int q = 0; q < 9; ++q) { fa0[q] = p[q]; fb0[q] = p[q + 2304]; }
    }
    CONV_CL(&smf[kg][buf][TCH + yl * TP + x0], fa1, fb1);
  }

  __syncthreads();
  double (*red)[8] = (double(*)[8]) & smf[0][0][0];
  if (kg < 3) {
    double* rp = red[(kg << 7) + t];
    rp[0] = aA[0]; rp[1] = aA[1]; rp[2] = aA[2]; rp[3] = aA[3];
    rp[4] = aB[0]; rp[5] = aB[1]; rp[6] = aB[2]; rp[7] = aB[3];
  }
  __syncthreads();
  if (kg == 3) {
    const double bA = (double)bias[co0], bB = (double)bias[co0 + 1];
    const double* r0 = red[t];
    const double* r1 = red[128 + t];
    const double* r2 = red[256 + t];
    const int y = h16 + yl;
    float4 RA, RB;
    RA.x = (float)fmax(r0[0] + r1[0] + r2[0] + aA[0] + bA, 0.0);
    RA.y = (float)fmax(r0[1] + r1[1] + r2[1] + aA[1] + bA, 0.0);
    RA.z = (float)fmax(r0[2] + r1[2] + r2[2] + aA[2] + bA, 0.0);
    RA.w = (float)fmax(r0[3] + r1[3] + r2[3] + aA[3] + bA, 0.0);
    RB.x = (float)fmax(r0[4] + r1[4] + r2[4] + aB[0] + bB, 0.0);
    RB.y = (float)fmax(r0[5] + r1[5] + r2[5] + aB[1] + bB, 0.0);
    RB.z = (float)fmax(r0[6] + r1[6] + r2[6] + aB[2] + bB, 0.0);
    RB.w = (float)fmax(r0[7] + r1[7] + r2[7] + aB[3] + bB, 0.0);
    *(float4*)&xout[(co0 << 10) + (y << 5) + x0] = RA;
    *(float4*)&xout[((co0 + 1) << 10) + (y << 5) + x0] = RB;
  }
}

// ========== fallback conv (small ws) ========================================
#define CPITCH 38
#define CCHS   (18 * CPITCH)
__global__ __launch_bounds__(256) void conv3x3_relu_fb_k(
    const float* __restrict__ feat, const float* __restrict__ w,
    const float* __restrict__ bias, float* __restrict__ xout)
{
  __shared__ float il[2][8 * CCHS];
  const int cp = blockIdx.x >> 1, h = blockIdx.x & 1;
  const int tid = threadIdx.x;
  const int h16 = h << 4;
  const int co0 = cp << 1;
  for (int i = tid; i < 8 * CCHS; i += 256) { il[0][i] = 0.0f; il[1][i] = 0.0f; }
  const int yl = tid >> 4;
  const int x0 = (tid & 15) << 1;
  double aA0 = 0.0, aA1 = 0.0, aB0 = 0.0, aB1 = 0.0;
  const float4* feat4 = (const float4*)feat;
  float4 pf[5]; int pch[5], pt[5], pc4[5], pok[5];
  #pragma unroll
  for (int k = 0; k < 5; ++k) {
    const int i = tid + (k << 8);
    const int ch = i / 144, rem = i - ch * 144;
    const int t = rem >> 3, c4 = rem & 7;
    const int g = h16 - 1 + t;
    pch[k] = ch; pt[k] = t; pc4[k] = c4;
    pok[k] = (i < 1152) && ((unsigned)g < 32u);
    pf[k] = pok[k] ? feat4[(ch << 8) + (g << 3) + c4] : float4{0.f,0.f,0.f,0.f};
  }
  __syncthreads();
  for (int cc = 0; cc < 256; cc += 8) {
    const int buf = (cc >> 3) & 1;
    #pragma unroll
    for (int k = 0; k < 5; ++k)
      if (pok[k]) {
        float* p = &il[buf][pch[k] * CCHS + pt[k] * CPITCH + (pc4[k] << 2) + 1];
        p[0] = pf[k].x; p[1] = pf[k].y; p[2] = pf[k].z; p[3] = pf[k].w;
      }
    if (cc + 8 < 256) {
      #pragma unroll
      for (int k = 0; k < 5; ++k) {
        const int g = h16 - 1 + pt[k];
        if (pok[k]) pf[k] = feat4[((cc + 8 + pch[k]) << 8) + (g << 3) + pc4[k]];
      }
    }
    __syncthreads();
    #pragma unroll
    for (int cl = 0; cl < 8; ++cl) {
      const float* wAp = w + co0 * 2304 + (cc + cl) * 9;
      const float* wBp = wAp + 2304;
      double wa[9], wb[9];
      #pragma unroll
      for (int q = 0; q < 9; ++q) { wa[q] = (double)wAp[q]; wb[q] = (double)wBp[q]; }
      const float* ir = &il[buf][cl * CCHS + yl * CPITCH + x0];
      #pragma unroll
      for (int ky = 0; ky < 3; ++ky) {
        const float2 q0 = *(const float2*)(ir + ky * CPITCH);
        const float2 q1 = *(const float2*)(ir + ky * CPITCH + 2);
        const double v0 = (double)q0.x, v1 = (double)q0.y;
        const double v2 = (double)q1.x, v3 = (double)q1.y;
        aA0 += v0 * wa[3*ky+0] + v1 * wa[3*ky+1] + v2 * wa[3*ky+2];
        aA1 += v1 * wa[3*ky+0] + v2 * wa[3*ky+1] + v3 * wa[3*ky+2];
        aB0 += v0 * wb[3*ky+0] + v1 * wb[3*ky+1] + v2 * wb[3*ky+2];
        aB1 += v1 * wb[3*ky+0] + v2 * wb[3*ky+1] + v3 * wb[3*ky+2];
      }
    }
  }
  const double bA = (double)bias[co0], bB = (double)bias[co0 + 1];
  const int y = h16 + yl;
  float2 rA, rB;
  rA.x = (float)fmax(aA0 + bA, 0.0); rA.y = (float)fmax(aA1 + bA, 0.0);
  rB.x = (float)fmax(aB0 + bB, 0.0); rB.y = (float)fmax(aB1 + bB, 0.0);
  *(float2*)&xout[(co0 << 10) + (y << 5) + x0] = rA;
  *(float2*)&xout[((co0 + 1) << 10) + (y << 5) + x0] = rB;
}

// ================= 1x1 heads ================================================
__global__ __launch_bounds__(256) void head1x1_k(
    const float* __restrict__ x,
    const float* __restrict__ cls_w, const float* __restrict__ cls_b,
    const float* __restrict__ bbox_w, const float* __restrict__ bbox_b,
    float* __restrict__ out, float* __restrict__ bbox_out)
{
  __shared__ float wl[512];
  const int bid = blockIdx.x;
  const int co = bid >> 2;
  const int px = ((bid & 3) << 8) | threadIdx.x;
  const bool is_cls = co < 18;
  const float* wsrc = is_cls ? (cls_w + co * 512) : (bbox_w + (co - 18) * 512);
  for (int i = threadIdx.x; i < 512; i += 256) wl[i] = wsrc[i];
  __syncthreads();
  double acc0 = 0.0, acc1 = 0.0, acc2 = 0.0, acc3 = 0.0;
  #pragma unroll 4
  for (int c = 0; c < 512; c += 4) {
    acc0 += (double)x[((c + 0) << 10) | px] * (double)wl[c + 0];
    acc1 += (double)x[((c + 1) << 10) | px] * (double)wl[c + 1];
    acc2 += (double)x[((c + 2) << 10) | px] * (double)wl[c + 2];
    acc3 += (double)x[((c + 3) << 10) | px] * (double)wl[c + 3];
  }
  double acc = ((acc0 + acc1) + (acc2 + acc3)) +
               (double)(is_cls ? cls_b[co] : bbox_b[co - 18]);
  if (is_cls)
    out[36864 + (co << 10) + px] = (float)(1.0 / (1.0 + exp(-acc)));
  else
    bbox_out[((co - 18) << 10) + px] = (float)acc;
}

// ============ anchors + box decode + clip + key build =======================
__global__ __launch_bounds__(256) void proposals_k(
    const float* __restrict__ bbox, const int* __restrict__ imgsz,
    const float* __restrict__ out, float* __restrict__ props,
    u64* __restrict__ keys, unsigned* __restrict__ rank)
{
  const int r = blockIdx.x * 256 + threadIdx.x;
  if (r >= 9216) return;
  const float4 d = ((const float4*)bbox)[r];
  const int cell = r / 9, a = r - cell * 9;
  const int ix = cell & 31, iy = cell >> 5;
  const int ri = a / 3, si = a - ri * 3;
  const double ratio = (ri == 0) ? 0.5 : (ri == 1 ? 1.0 : 2.0);
  const double scale = (si == 0) ? 128.0 : (si == 1 ? 256.0 : 512.0);
  const double hr = sqrt(ratio), wr = 1.0 / hr;
  const double bx = nearbyint(wr * scale * 0.5);
  const double by = nearbyint(hr * scale * 0.5);
  const double cx = ix * 16.0, cy = iy * 16.0;
  const double w = 2.0 * bx, hh = 2.0 * by;
  const double pcx = (double)d.x * w + cx;
  const double pcy = (double)d.y * hh + cy;
  const double pw = exp((double)d.z) * w;
  const double ph = exp((double)d.w) * hh;
  const double im = (double)imgsz[0];
  float4 o;
  o.x = (float)fmin(fmax(pcx - 0.5 * pw, 0.0), im);
  o.y = (float)fmin(fmax(pcy - 0.5 * ph, 0.0), im);
  o.z = (float)fmin(fmax(pcx + 0.5 * pw, 0.0), im);
  o.w = (float)fmin(fmax(pcy + 0.5 * ph, 0.0), im);
  ((float4*)props)[r] = o;
  const float s = out[36864 + ((2 * (r >> 10) + 1) << 10) + (r & 1023)];
  keys[r] = ((u64)__float_as_uint(s) << 32) | (unsigned)(0x7FFFFFFF - r);
  rank[r] = 0u;
}

// ================= rank sort ================================================
__global__ __launch_bounds__(256) void rank_k(
    const u64* __restrict__ keys, unsigned* __restrict__ rank)
{
  const int jt = blockIdx.x % 36, ic = blockIdx.x / 36;
  const int j = jt * 256 + threadIdx.x;
  const u64 kj = keys[j];
  const int lane = threadIdx.x & 63;
  const int base = ic * 576;
  unsigned lo[9], hi[9];
  #pragma unroll
  for (int rr = 0; rr < 9; ++rr) {
    const u64 k = keys[base + rr * 64 + lane];
    lo[rr] = (unsigned)k; hi[rr] = (unsigned)(k >> 32);
  }
  unsigned cnt = 0;
  #pragma unroll
  for (int rr = 0; rr < 9; ++rr) {
    #pragma unroll
    for (int l = 0; l < 64; ++l) {
      const unsigned llo = (unsigned)__builtin_amdgcn_readlane((int)lo[rr], l);
      const unsigned lhi = (unsigned)__builtin_amdgcn_readlane((int)hi[rr], l);
      const u64 ki = ((u64)lhi << 32) | llo;
      cnt += (ki > kj) ? 1u : 0u;
    }
  }
  atomicAdd(&rank[j], cnt);
}

// ================= scatter into sorted order ================================
__global__ __launch_bounds__(256) void scatter_k(
    const u64* __restrict__ keys, const unsigned* __restrict__ rank,
    const float* __restrict__ props, u64* __restrict__ skeys,
    float4* __restrict__ sboxes)
{
  const int r = blockIdx.x * 256 + threadIdx.x;
  if (r >= 9216) return;
  const unsigned rk = rank[r];
  skeys[rk] = keys[r];
  sboxes[rk] = ((const float4*)props)[r];
}

// ====== suppression bitmask + intra-word columns (chunk 64, LDS boxes) ======
// grid (144 i-chunks x 36 word-quads), 256 thr = 4 waves, wave wv owns
// W = 4*by+wv. Chunk = 64 i's staged in LDS; short tails -> high parallelism.
__global__ __launch_bounds__(256) void mask_k(
    const float4* __restrict__ sb4, u64* __restrict__ mask,
    u64* __restrict__ intra)
{
  __shared__ __align__(16) float4 ib[64];
  const int ci = blockIdx.x;                  // 0..143
  const int Wb = blockIdx.y << 2;
  const int i_lo = ci << 6;
  const int i_hi = min(i_lo + 64, (Wb + 4) << 6);
  if (i_lo >= i_hi) return;                   // uniform across block
  const int wv = threadIdx.x >> 6, lane = threadIdx.x & 63;
  const int W = Wb + wv;
  const int cnt = i_hi - i_lo;
  if (threadIdx.x < cnt) ib[threadIdx.x] = sb4[i_lo + threadIdx.x];
  __syncthreads();
  const float4 bj = sb4[(W << 6) + lane];
  const float areaJ = (bj.z - bj.x) * (bj.w - bj.y);
  const int wbase = W << 6;
  const int n = min(i_hi, wbase + 64) - i_lo;   // may be <=0
  u64 intr = 0ULL;
  #pragma unroll 8
  for (int k = 0; k < n; ++k) {
    const float4 bi = ib[k];
    const float areaI = (bi.z - bi.x) * (bi.w - bi.y);
    const float ix1 = fmaxf(bj.x, bi.x), iy1 = fmaxf(bj.y, bi.y);
    const float ix2 = fminf(bj.z, bi.z), iy2 = fminf(bj.w, bi.w);
    const float iw = fmaxf(ix2 - ix1, 0.0f), ih = fmaxf(iy2 - iy1, 0.0f);
    const double inter = (double)iw * (double)ih;
    const double uni = (double)areaJ + (double)areaI - inter + 1e-9;
    const bool pred = inter > 0.3 * uni;
    const u64 bal = __ballot(pred);
    const int i = i_lo + k;
    if (lane == 0) mask[(size_t)i * 144 + W] = bal;
    if (i >= wbase) intr |= pred ? (1ULL << (i - wbase)) : 0ULL;
  }
  if (ci == W) intra[wbase + lane] = intr;      // diagonal chunk (64 = word)
}

// ====== sweep v4: 8-word supergroups, staging overlapped with resolve =======
// 1 block x 1024 thr. 18 sgs of 8 words (512 boxes). Per sg iteration:
//  phase A: waves 0-7 PULL prior-kept rows' sg-words into supS[sg&1]
//           (kept list complete through sg-1); waves 8-15 STAGE sg+1's
//           sub-mask + intra into the other LDS buffer.
//  phase B: wave0 resolves sg's 8 words from LDS only (intra-ballot + <=8
//           kept rows per ds_read round); wave1 zeroes supS[(sg+1)&1].
// Exactness: words ascending; within-sg garbage only ANDs already-resolved
// words; cross-sg suppression via exact mask rows (pull). Same fp64 IoU
// predicate as reference order => identical keep set.
__global__ __launch_bounds__(1024) void sweep_out_k(
    const u64* __restrict__ mask, const u64* __restrict__ intra,
    const u64* __restrict__ skeys, const float4* __restrict__ sboxes,
    float* __restrict__ out)
{
  extern __shared__ __align__(16) char sm[];
  u64* subm   = (u64*)sm;                        // 2*4096 u64 = 65536 B
  u64* intraS = subm + 8192;                     // 2*512 u64  = 8192 B
  u64* supS   = intraS + 1024;                   // 2*8 u64    = 128 B
  u64* keptS  = supS + 16;                       // 144 u64    = 1152 B
  unsigned short* kpl = (unsigned short*)(keptS + 144);  // 9216 u16 = 18432 B
  int* kcnt = (int*)(kpl + 9216);                // 4 B  (total 93,444)

  const int tid = threadIdx.x;
  const int lane = tid & 63, wv = tid >> 6;
  if (tid == 0) *kcnt = 0;
  if (tid < 144) keptS[tid] = 0ULL;
  if (tid < 16) supS[tid] = 0ULL;
  // stage sg 0 into buffer 0
  if (tid < 512) {
    const int wq = tid & 7, r0 = tid >> 3;       // r0: 0..63
    #pragma unroll
    for (int k = 0; k < 8; ++k) {
      const int i = r0 + (k << 6);               // 0..511
      subm[i * 8 + wq] = mask[(size_t)i * 144 + wq];
    }
    if (wq == 0) intraS[r0] = intra[r0];
    if (wq == 1) intraS[64 + r0] = intra[64 + r0];
    if (wq == 2) intraS[128 + r0] = intra[128 + r0];
    if (wq == 3) intraS[192 + r0] = intra[192 + r0];
    if (wq == 4) intraS[256 + r0] = intra[256 + r0];
    if (wq == 5) intraS[320 + r0] = intra[320 + r0];
    if (wq == 6) intraS[384 + r0] = intra[384 + r0];
    if (wq == 7) intraS[448 + r0] = intra[448 + r0];
  }
  __syncthreads();

  for (int sg = 0; sg < 18; ++sg) {
    const int buf = sg & 1;
    const int wbase = sg << 3;
    const int ibase = wbase << 6;
    // ---- phase A ----
    if (tid < 512) {                             // pull(sg) into supS[buf]
      const int K = *kcnt;
      const int wq = tid & 7;
      u64 acc = 0ULL;
      int jj = tid >> 3;                         // 64 streams, stride 64
      for (; jj + 7 * 64 < K; jj += 8 * 64) {
        const u64 v0 = mask[(size_t)kpl[jj + 0 * 64] * 144 + wbase + wq];
        const u64 v1 = mask[(size_t)kpl[jj + 1 * 64] * 144 + wbase + wq];
        const u64 v2 = mask[(size_t)kpl[jj + 2 * 64] * 144 + wbase + wq];
        const u64 v3 = mask[(size_t)kpl[jj + 3 * 64] * 144 + wbase + wq];
        const u64 v4 = mask[(size_t)kpl[jj + 4 * 64] * 144 + wbase + wq];
        const u64 v5 = mask[(size_t)kpl[jj + 5 * 64] * 144 + wbase + wq];
        const u64 v6 = mask[(size_t)kpl[jj + 6 * 64] * 144 + wbase + wq];
        const u64 v7 = mask[(size_t)kpl[jj + 7 * 64] * 144 + wbase + wq];
        acc |= ((v0 | v1) | (v2 | v3)) | ((v4 | v5) | (v6 | v7));
      }
      for (; jj < K; jj += 64)
        acc |= mask[(size_t)kpl[jj] * 144 + wbase + wq];
      if (acc) {
        atomicOr((unsigned*)&supS[(buf << 3) + wq], (unsigned)acc);
        atomicOr(((unsigned*)&supS[(buf << 3) + wq]) + 1, (unsigned)(acc >> 32));
      }
    } else if (sg + 1 < 18) {                    // stage(sg+1) into buf^1
      const int s = tid - 512;
      const int wq = s & 7, r0 = s >> 3;
      const int nb = 1 - buf;
      const int ib2 = (sg + 1) << 9;
      const int wb2 = (sg + 1) << 3;
      #pragma unroll
      for (int k = 0; k < 8; ++k) {
        const int i = r0 + (k << 6);
        subm[(nb << 12) + i * 8 + wq] = mask[(size_t)(ib2 + i) * 144 + wb2 + wq];
      }
      if (wq < 8) {
        const int idx = (wq << 6) + r0;          // 0..511
        intraS[(nb << 9) + idx] = intra[ib2 + idx];
      }
    }
    __syncthreads();
    // ---- phase B ----
    if (wv == 0) {
      u64 myAlive = (lane < 8) ? ~supS[(buf << 3) + lane] : 0ULL;
      const u64* sub = subm + (buf << 12);
      const u64* its = intraS + (buf << 9);
      for (int w = 0; w < 8; ++w) {
        const u64 av = __shfl(myAlive, w, 64);
        if (av == 0ULL) continue;
        const u64 il_ = its[(w << 6) + lane];
        u64 cand = av, keptw = 0ULL;
        while (cand) {
          const int b = (int)__builtin_ctzll(cand);   // uniform
          keptw |= 1ULL << b;
          cand &= ~(1ULL << b);
          const u64 sup = __ballot((il_ >> b) & 1ULL);
          cand &= ~sup;
        }
        if (lane == 0) {
          keptS[wbase + w] = keptw;
          int K = *kcnt;
          u64 t = keptw;
          while (t) {
            const int b = (int)__builtin_ctzll(t); t &= t - 1ULL;
            kpl[K++] = (unsigned short)(ibase + (w << 6) + b);
          }
          *kcnt = K;
        }
        // apply kept rows (batch 8 per ds_read round)
        u64 t = keptw;
        while (t) {
          int bs[8]; int n = 0;
          #pragma unroll
          for (int s = 0; s < 8; ++s) {
            if (t) { bs[s] = (int)__builtin_ctzll(t); t &= t - 1ULL; n = s + 1; }
            else bs[s] = 0;
          }
          const int kk = lane >> 3, wq = lane & 7;
          u64 r = (kk < n) ? sub[((w << 6) + bs[kk]) * 8 + wq] : 0ULL;
          r |= __shfl_down(r, 8, 64);
          r |= __shfl_down(r, 16, 64);
          r |= __shfl_down(r, 32, 64);
          // lanes 0..7 hold OR of all <=8 kept rows for word wbase+lane
          myAlive &= ~r;
        }
      }
    } else if (wv == 1) {
      if (lane < 8) supS[((1 - buf) << 3) + lane] = 0ULL;  // zero for next pull
    }
    __syncthreads();                             // kept/kpl visible for pull
  }
  for (int i = tid; i < 9216; i += 1024) {
    const u64 key = skeys[i];
    const int orig = 0x7FFFFFFF - (int)(unsigned)(key & 0xFFFFFFFFULL);
    const bool kp = (keptS[i >> 6] >> (i & 63)) & 1ULL;
    float4 ob = sboxes[i];
    if (!kp) { ob.x = 0.f; ob.y = 0.f; ob.z = 0.f; ob.w = 0.f; }
    ((float4*)out)[orig] = ob;
    out[55296 + orig] = kp ? 1.0f : 0.0f;
  }
}

// ================= fallback NMS (small ws) ==================================
__global__ __launch_bounds__(1024) void nms_fallback_k(
    const float* __restrict__ props, float* __restrict__ out)
{
  __shared__ u64 wmax[16];
  __shared__ float4 curBoxS;
  const int tid = threadIdx.x, wid = tid >> 6, lane = tid & 63;
  u64 key[9];
  float4 box[9];
  #pragma unroll
  for (int j = 0; j < 9; ++j) {
    const int r = tid + (j << 10);
    box[j] = ((const float4*)props)[r];
    const float s = out[36864 + ((2 * (r >> 10) + 1) << 10) + (r & 1023)];
    key[j] = ((u64)__float_as_uint(s) << 32) | (unsigned)(0x7FFFFFFF - r);
  }
  unsigned kept = 0;
  for (;;) {
    u64 m = key[0];
    #pragma unroll
    for (int j = 1; j < 9; ++j) m = key[j] > m ? key[j] : m;
    #pragma unroll
    for (int off = 32; off; off >>= 1) {
      const u64 o = __shfl_down(m, off, 64);
      if (o > m) m = o;
    }
    if (lane == 0) wmax[wid] = m;
    __syncthreads();
    u64 K = wmax[0];
    #pragma unroll
    for (int wv2 = 1; wv2 < 16; ++wv2) { const u64 t = wmax[wv2]; if (t > K) K = t; }
    if (K == 0) break;
    #pragma unroll
    for (int j = 0; j < 9; ++j)
      if (key[j] == K) { curBoxS = box[j]; key[j] = 0; kept |= 1u << j; }
    __syncthreads();
    const float4 cb = curBoxS;
    const float areaC = (cb.z - cb.x) * (cb.w - cb.y);
    #pragma unroll
    for (int j = 0; j < 9; ++j) {
      if (key[j]) {
        const float4 b = box[j];
        const float ix1 = fmaxf(b.x, cb.x), iy1 = fmaxf(b.y, cb.y);
        const float ix2 = fminf(b.z, cb.z), iy2 = fminf(b.w, cb.w);
        const float iw = fmaxf(ix2 - ix1, 0.0f), ih = fmaxf(iy2 - iy1, 0.0f);
        const float areaB = (b.z - b.x) * (b.w - b.y);
        const double inter = (double)iw * (double)ih;
        const double uni = (double)areaB + (double)areaC - inter + 1e-9;
        if (inter > 0.3 * uni) key[j] = 0;
      }
    }
    __syncthreads();
  }
  #pragma unroll
  for (int j = 0; j < 9; ++j) {
    const int r = tid + (j << 10);
    const bool kp = (kept >> j) & 1u;
    float4 ob = box[j];
    if (!kp) { ob.x = 0.f; ob.y = 0.f; ob.z = 0.f; ob.w = 0.f; }
    ((float4*)out)[r] = ob;
    out[55296 + r] = kp ? 1.0f : 0.0f;
  }
}

// ============================================================================
extern "C" void kernel_launch(void* const* d_in, const int* in_sizes, int n_in,
                              void* d_out, int out_size, void* d_ws, size_t ws_size,
                              hipStream_t stream)
{
  const float* feat   = (const float*)d_in[0];
  const int*   imgsz  = (const int*)d_in[1];
  const float* conv_w = (const float*)d_in[2];
  const float* conv_b = (const float*)d_in[3];
  const float* cls_w  = (const float*)d_in[4];
  const float* cls_b  = (const float*)d_in[5];
  const float* bbox_w = (const float*)d_in[6];
  const float* bbox_b = (const float*)d_in[7];
  float* out = (float*)d_out;
  char*  ws  = (char*)d_ws;
  float* x      = (float*)(ws + X_B);
  float* bbox   = (float*)(ws + BBOX_B);
  float* props  = (float*)(ws + PROPS_B);
  u64*      keys  = (u64*)(ws + KEYS_B);
  unsigned* rankp = (unsigned*)(ws + RANK_B);
  u64*      skeys = (u64*)(ws + SKEYS_B);
  float4*   sboxs = (float4*)(ws + SBOX_B);
  u64*      maskp = (u64*)(ws + MASK_B);
  u64*      intrp = (u64*)(ws + INTRA_B);

  if (ws_size >= (size_t)WS_NEED) {
    hipLaunchKernelGGL(conv3x3_relu_k, dim3(512), dim3(512), 0, stream,
                       feat, conv_w, conv_b, x);
    hipLaunchKernelGGL(head1x1_k, dim3(216), dim3(256), 0, stream,
                       x, cls_w, cls_b, bbox_w, bbox_b, out, bbox);
    hipLaunchKernelGGL(proposals_k, dim3(36), dim3(256), 0, stream,
                       bbox, imgsz, out, props, keys, rankp);
    hipLaunchKernelGGL(rank_k, dim3(576), dim3(256), 0, stream, keys, rankp);
    hipLaunchKernelGGL(scatter_k, dim3(36), dim3(256), 0, stream,
                       keys, rankp, props, skeys, sboxs);
    hipLaunchKernelGGL(mask_k, dim3(144, 36), dim3(256), 0, stream,
                       sboxs, maskp, intrp);
    hipLaunchKernelGGL(sweep_out_k, dim3(1), dim3(1024), 93444, stream,
                       maskp, intrp, skeys, sboxs, out);
  } else {
    hipLaunchKernelGGL(conv3x3_relu_fb_k, dim3(512), dim3(256), 0, stream,
                       feat, conv_w, conv_b, x);
    hipLaunchKernelGGL(head1x1_k, dim3(216), dim3(256), 0, stream,
                       x, cls_w, cls_b, bbox_w, bbox_b, out, bbox);
    hipLaunchKernelGGL(proposals_k, dim3(36), dim3(256), 0, stream,
                       bbox, imgsz, out, props, keys, rankp);
    hipLaunchKernelGGL(nms_fallback_k, dim3(1), dim3(1024), 0, stream,
                       props, out);
  }
}